// Round 9
// baseline (79.499 us; speedup 1.0000x reference)
//
#include <hip/hip_runtime.h>

using short8 = __attribute__((ext_vector_type(8))) short;
using h8     = __attribute__((ext_vector_type(8))) _Float16;
using h2     = __attribute__((ext_vector_type(2))) _Float16;
using f32x4  = __attribute__((ext_vector_type(4))) float;

#define NB  16
#define NTH 1024
// ws layout (ushort units, all f16 bits)
#define WBIN_OFF 0         // [64 n][192 k]
#define WFIN_OFF 12288     // [160 n][64 k]
#define EMBO_OFF 22528     // [100 r][64 k]
#define LTAB_OFF 28928     // [6 p][100 v][64 n]
#define WS_USHORTS 67328

__device__ __forceinline__ unsigned short f2h_bits(float v) {
    _Float16 h = (_Float16)v;
    return *reinterpret_cast<unsigned short*>(&h);
}
__device__ __forceinline__ h8 ld8h(const unsigned short* p) {
    return *reinterpret_cast<const h8*>(p);
}
__device__ __forceinline__ short8 ld8s(const unsigned short* p) {
    return *reinterpret_cast<const short8*>(p);
}
__device__ __forceinline__ f32x4 mf(h8 a, h8 b, f32x4 c) {
    return __builtin_amdgcn_mfma_f32_16x16x32_f16(a, b, c, 0, 0, 0);
}

// ---------------- prep: build f16 weights + leaf lookup tables --------------
__global__ void prep_kernel(const float* __restrict__ emb_pred,
                            const float* __restrict__ emb_var,
                            const float* __restrict__ emb_op,
                            const float* __restrict__ W_pred,
                            const float* __restrict__ W_bin,
                            const float* __restrict__ W_final,
                            unsigned short* __restrict__ ws) {
    for (int i = blockIdx.x * blockDim.x + threadIdx.x; i < WS_USHORTS;
         i += gridDim.x * blockDim.x) {
        float v = 0.f;
        if (i < WFIN_OFF) {                      // W_bin [64][192]
            int n = i / 192, k = i - n * 192, p = k >> 6, j = k & 63;
            if (n < 50 && j < 50) v = W_bin[n * 150 + p * 50 + j];
        } else if (i < EMBO_OFF) {               // W_final [160][64]
            int t = i - WFIN_OFF, o = t >> 6, k = t & 63;
            if (o < 155 && k < 50) v = W_final[o * 50 + k];
        } else if (i < LTAB_OFF) {               // emb_op [100][64]
            int t = i - EMBO_OFF, r = t >> 6, j = t & 63;
            if (j < 50) v = emb_op[r * 50 + j];
        } else {                                 // leaf tables [6][100][64]
            int t = i - LTAB_OFF;
            int p = t / 6400, rest = t - p * 6400, vv = rest >> 6, n = rest & 63;
            if (n < 50) {
                const float* e = (p == 0) ? (emb_pred + vv * 50) : (emb_var + vv * 50);
                const float* wr = W_pred + n * 300 + p * 50;
                float acc = 0.f;
                for (int k = 0; k < 50; ++k) acc += e[k] * wr[k];
                v = acc;
            }
        }
        ws[i] = f2h_bits(v);
    }
}

// one tree node, compile-time N-tile subset [NT0, NT0+NTN)
#define TNODE(NT0, NTN, CL, CR, GN, DST) do {                                   \
    const unsigned short* rl_ = s_x[CL];                                        \
    const unsigned short* rr_ = s_x[CR];                                        \
    int r_ = s_op[(GN) * 16 + l15];                                             \
    h8 aL0 = ld8h(rl_ + l15 * 64 + ((quad ^ (l15 & 7)) << 3));                  \
    h8 aL1 = ld8h(rl_ + l15 * 64 + (((quad + 4) ^ (l15 & 7)) << 3));            \
    h8 aO0 = ld8h(s_embop + r_ * 64 + ((quad ^ (r_ & 7)) << 3));                \
    h8 aO1 = ld8h(s_embop + r_ * 64 + (((quad + 4) ^ (r_ & 7)) << 3));          \
    h8 aR0 = ld8h(rr_ + l15 * 64 + ((quad ^ (l15 & 7)) << 3));                  \
    h8 aR1 = ld8h(rr_ + l15 * 64 + (((quad + 4) ^ (l15 & 7)) << 3));            \
    f32x4 acc_[NTN];                                                            \
    _Pragma("unroll") for (int i_ = 0; i_ < (NTN); ++i_) {                      \
        acc_[i_] = (f32x4){0.f, 0.f, 0.f, 0.f};                                 \
        acc_[i_] = mf(aL0, wb[0][0][(NT0) + i_], acc_[i_]);                     \
        acc_[i_] = mf(aL1, wb[0][1][(NT0) + i_], acc_[i_]);                     \
        acc_[i_] = mf(aO0, wb[1][0][(NT0) + i_], acc_[i_]);                     \
        acc_[i_] = mf(aO1, wb[1][1][(NT0) + i_], acc_[i_]);                     \
        acc_[i_] = mf(aR0, wb[2][0][(NT0) + i_], acc_[i_]);                     \
        acc_[i_] = mf(aR1, wb[2][1][(NT0) + i_], acc_[i_]);                     \
    }                                                                           \
    unsigned short* drow_ = s_x[DST];                                           \
    _Pragma("unroll") for (int i_ = 0; i_ < (NTN); ++i_) {                      \
        int n_ = ((NT0) + i_) * 16 + l15;                                       \
        _Pragma("unroll") for (int q_ = 0; q_ < 4; ++q_) {                      \
            int m_ = quad * 4 + q_;                                             \
            float v_ = fmaxf(acc_[i_][q_] + biasb[(NT0) + i_], 0.f);            \
            drow_[m_ * 64 + (((n_ >> 3) ^ (m_ & 7)) << 3) + (n_ & 7)] = f2h_bits(v_); \
        }                                                                       \
    }                                                                           \
} while (0)

// ---------------- main fused kernel -----------------------------------------
// 1 block = 16 batch, 16 waves (4/SIMD). Row map (s_x):
//   leaves 0..63 | lev0 node j -> 2j (in-place, 1 wave/node, safe)
//   lev1 j: reads 4j,4j+2 -> 4j (1 wave/node) | lev2 j: reads 8j,8j+4 -> 8j+1
//   lev3 j: reads 16j+1,16j+9 -> 16j+2 | lev4 j: reads 32j+2,32j+18 -> 32j+3
//   root: reads 3,35 -> 1. Multi-wave nodes write DEAD rows (no in-level race).
// __launch_bounds__(1024, 1): R7's (1024,4) AND R8's default both produced a
// 64-VGPR cap (occupancy-greedy heuristic) -> wb_raw spill, 116+119 MB/dispatch
// scratch HBM traffic. ",1" requests 1 block/CU so allocator budget = 128 VGPR
// (flat-wg fit), which holds the ~90-VGPR working set with zero spill.
__global__ __launch_bounds__(NTH, 1) void formula_kernel(
    const int* __restrict__ pred_ids, const int* __restrict__ arg_ids,
    const int* __restrict__ op_ids,
    const float* __restrict__ b_pred, const float* __restrict__ b_bin,
    const float* __restrict__ b_final,
    const unsigned short* __restrict__ ws,
    float* __restrict__ out)
{
    __shared__ __align__(16) unsigned short s_x[64][1024];         // 131072 B
    __shared__ __align__(16) unsigned short s_embop[100 * 64];     //  12800 B
    __shared__ __align__(8)  unsigned char  s_ids[64][16][8];      //   8192 B
    __shared__ unsigned char s_op[63 * 16 + 16];                   //   1024 B

    const int tid  = threadIdx.x;
    const int b0   = blockIdx.x * NB;
    const int lane = tid & 63;
    const int w    = tid >> 6;       // wave 0..15
    const int l15  = lane & 15;
    const int quad = lane >> 4;
    const int cg   = tid & 7;        // constant col-group (leaf phase)

    // ---- stage op embeddings (swizzled by r&7) ----
    if (tid < 800) {
        int r = tid >> 3, s = tid & 7;
        *reinterpret_cast<short8*>(&s_embop[r * 64 + ((s ^ (r & 7)) << 3)]) =
            ld8s(ws + EMBO_OFF + r * 64 + s * 8);
    }
    // ---- stage ids: s_ids[leaf][m] = {pred, a0..a4, 0, 0} (1 per thread) ----
    {
        int m = tid >> 6, lf = tid & 63;
        unsigned char* rec = &s_ids[lf][m][0];
        rec[0] = (unsigned char)pred_ids[(b0 + m) * 64 + lf];
        #pragma unroll
        for (int a = 0; a < 5; ++a)
            rec[1 + a] = (unsigned char)arg_ids[(b0 + m) * 320 + lf * 5 + a];
        rec[6] = 0; rec[7] = 0;
    }
    // 1008 = 63*16: split on low-4 bits (m) / next bits (r) — exact enumeration
    if (tid < 63 * 16) {
        int r = tid >> 4, m = tid & 15;
        s_op[r * 16 + m] = (unsigned char)op_ids[(b0 + m) * 63 + r];
    }

    // ---- persistent W_bin fragments: all 4 N-tiles in regs ----
    short8 wb_raw[3][2][4];
    #pragma unroll
    for (int p = 0; p < 3; ++p)
        #pragma unroll
        for (int h = 0; h < 2; ++h)
            #pragma unroll
            for (int nt = 0; nt < 4; ++nt)
                wb_raw[p][h][nt] = ld8s(ws + WBIN_OFF + (nt * 16 + l15) * 192
                                        + p * 64 + (quad + 4 * h) * 8);
    h8 (&wb)[3][2][4] = reinterpret_cast<h8(&)[3][2][4]>(wb_raw);

    float biasb[4];
    #pragma unroll
    for (int nt = 0; nt < 4; ++nt) {
        int n = nt * 16 + l15;
        biasb[nt] = (n < 50) ? b_bin[n] : 0.f;
    }
    h2 bias2[4];
    #pragma unroll
    for (int k = 0; k < 4; ++k) {
        int n0 = cg * 8 + 2 * k, n1 = n0 + 1;
        bias2[k] = (h2){(_Float16)((n0 < 50) ? b_pred[n0] : 0.f),
                        (_Float16)((n1 < 50) ? b_pred[n1] : 0.f)};
    }
    const h2 z2 = (h2){(_Float16)0.f, (_Float16)0.f};

    __syncthreads();

    // ---- leaf layer: 64 leaves x 16 m x 8 cg = 8192 jobs, 8/thread.
    //      Tables read from GLOBAL (coalesced 8x128B lines per wave-load).
    #pragma unroll
    for (int p4 = 0; p4 < 8; ++p4) {
        int jj  = p4 * 128 + (tid >> 3);   // (leaf, m) id
        int lf  = jj >> 4;
        int m   = jj & 15;
        const unsigned int* ivp =
            reinterpret_cast<const unsigned int*>(&s_ids[lf][m][0]);
        unsigned int ix = ivp[0], iy = ivp[1];
        int r0 = ix & 255, r1 = (ix >> 8) & 255, r2 = (ix >> 16) & 255;
        int r3 = ix >> 24, r4 = iy & 255, r5 = (iy >> 8) & 255;
        h2 a0 = bias2[0], a1 = bias2[1], a2 = bias2[2], a3 = bias2[3];
        #define ACCT(ROW, P) {                                                  \
            h8 t_ = ld8h(ws + LTAB_OFF + (P) * 6400 + (ROW) * 64 + cg * 8);     \
            const h2* tp_ = reinterpret_cast<const h2*>(&t_);                   \
            a0 += tp_[0]; a1 += tp_[1]; a2 += tp_[2]; a3 += tp_[3]; }
        ACCT(r0, 0); ACCT(r1, 1); ACCT(r2, 2);
        ACCT(r3, 3); ACCT(r4, 4); ACCT(r5, 5);
        #undef ACCT
        a0 = __builtin_elementwise_max(a0, z2);
        a1 = __builtin_elementwise_max(a1, z2);
        a2 = __builtin_elementwise_max(a2, z2);
        a3 = __builtin_elementwise_max(a3, z2);
        union { h2 h[4]; short8 s; } u;
        u.h[0] = a0; u.h[1] = a1; u.h[2] = a2; u.h[3] = a3;
        *reinterpret_cast<short8*>(
            &s_x[lf][m * 64 + ((cg ^ (m & 7)) << 3)]) = u.s;
    }
    __syncthreads();

    // ---- lev0: 32 nodes, 2 per wave (in-place; 1 wave/node) ----
    #pragma unroll
    for (int i = 0; i < 2; ++i) {
        int j = w + 16 * i;
        TNODE(0, 4, 2 * j, 2 * j + 1, j, 2 * j);
    }
    __syncthreads();
    // ---- lev1: 16 nodes, 1 per wave (in-place; 1 wave/node) ----
    { int j = w; TNODE(0, 4, 4 * j, 4 * j + 2, 32 + j, 4 * j); }
    __syncthreads();
    // ---- lev2: 8 nodes x 2 waves -> dead row 8j+1 ----
    {
        int j = w >> 1;
        if ((w & 1) == 0) TNODE(0, 2, 8 * j, 8 * j + 4, 48 + j, 8 * j + 1);
        else              TNODE(2, 2, 8 * j, 8 * j + 4, 48 + j, 8 * j + 1);
    }
    __syncthreads();
    // ---- lev3: 4 nodes x 4 waves -> dead row 16j+2 ----
    {
        int j = w >> 2;
        switch (w & 3) {
            case 0: TNODE(0, 1, 16 * j + 1, 16 * j + 9, 56 + j, 16 * j + 2); break;
            case 1: TNODE(1, 1, 16 * j + 1, 16 * j + 9, 56 + j, 16 * j + 2); break;
            case 2: TNODE(2, 1, 16 * j + 1, 16 * j + 9, 56 + j, 16 * j + 2); break;
            default: TNODE(3, 1, 16 * j + 1, 16 * j + 9, 56 + j, 16 * j + 2); break;
        }
    }
    __syncthreads();
    // ---- lev4: 2 nodes x 4 waves (waves 0..7) -> dead row 32j+3 ----
    if (w < 8) {
        int j = w >> 2;
        switch (w & 3) {
            case 0: TNODE(0, 1, 32 * j + 2, 32 * j + 18, 60 + j, 32 * j + 3); break;
            case 1: TNODE(1, 1, 32 * j + 2, 32 * j + 18, 60 + j, 32 * j + 3); break;
            case 2: TNODE(2, 1, 32 * j + 2, 32 * j + 18, 60 + j, 32 * j + 3); break;
            default: TNODE(3, 1, 32 * j + 2, 32 * j + 18, 60 + j, 32 * j + 3); break;
        }
    }
    __syncthreads();
    // ---- lev5 (root, waves 0..3): reads rows 3,35 -> dead row 1 ----
    if (w < 4) {
        switch (w) {
            case 0: TNODE(0, 1, 3, 35, 62, 1); break;
            case 1: TNODE(1, 1, 3, 35, 62, 1); break;
            case 2: TNODE(2, 1, 3, 35, 62, 1); break;
            default: TNODE(3, 1, 3, 35, 62, 1); break;
        }
    }
    __syncthreads();

    // ---- final head via MFMA: 10 N-tiles over waves 0..9 (root = row 1) ----
    if (w < 10) {
        f32x4 acc = {0.f, 0.f, 0.f, 0.f};
        int n2 = w * 16 + l15;
        const unsigned short* rroot = s_x[1];
        h8 x0 = ld8h(rroot + l15 * 64 + ((quad ^ (l15 & 7)) << 3));
        h8 x1 = ld8h(rroot + l15 * 64 + (((quad + 4) ^ (l15 & 7)) << 3));
        acc = mf(x0, ld8h(ws + WFIN_OFF + n2 * 64 + quad * 8), acc);
        acc = mf(x1, ld8h(ws + WFIN_OFF + n2 * 64 + (quad + 4) * 8), acc);
        if (n2 < 155) {
            float bias = b_final[n2];
            #pragma unroll
            for (int q = 0; q < 4; ++q) {
                int m = quad * 4 + q;
                out[(b0 + m) * 155 + n2] = acc[q] + bias;
            }
        }
    }
}

extern "C" void kernel_launch(void* const* d_in, const int* in_sizes, int n_in,
                              void* d_out, int out_size, void* d_ws, size_t ws_size,
                              hipStream_t stream) {
    const int*   pred_ids = (const int*)  d_in[0];
    const int*   arg_ids  = (const int*)  d_in[1];
    const int*   op_ids   = (const int*)  d_in[2];
    const float* emb_pred = (const float*)d_in[3];
    const float* emb_var  = (const float*)d_in[4];
    const float* emb_op   = (const float*)d_in[5];
    const float* W_pred   = (const float*)d_in[6];
    const float* b_pred   = (const float*)d_in[7];
    const float* W_bin    = (const float*)d_in[8];
    const float* b_bin    = (const float*)d_in[9];
    const float* W_final  = (const float*)d_in[10];
    const float* b_final  = (const float*)d_in[11];
    unsigned short* ws = (unsigned short*)d_ws;
    float* out = (float*)d_out;

    hipLaunchKernelGGL(prep_kernel, dim3(256), dim3(256), 0, stream,
                       emb_pred, emb_var, emb_op, W_pred, W_bin, W_final, ws);
    hipLaunchKernelGGL(formula_kernel, dim3(4096 / NB), dim3(NTH), 0, stream,
                       pred_ids, arg_ids, op_ids, b_pred, b_bin, b_final,
                       (const unsigned short*)ws, out);
}

// Round 10
// 31.829 us; speedup vs baseline: 2.4977x; 2.4977x over previous
//
#include <hip/hip_runtime.h>

using short8 = __attribute__((ext_vector_type(8))) short;
using h8     = __attribute__((ext_vector_type(8))) _Float16;
using h2     = __attribute__((ext_vector_type(2))) _Float16;
using f32x4  = __attribute__((ext_vector_type(4))) float;

#define NB  16
#define NTH 512
// ws layout (ushort units, all f16 bits)
#define WBIN_OFF 0         // [64 n][192 k]
#define WFIN_OFF 12288     // [160 n][64 k]
#define EMBO_OFF 22528     // [100 r][64 k]
#define LTAB_OFF 28928     // [6 p][100 v][64 n]
#define WS_USHORTS 67328

__device__ __forceinline__ unsigned short f2h_bits(float v) {
    _Float16 h = (_Float16)v;
    return *reinterpret_cast<unsigned short*>(&h);
}
__device__ __forceinline__ h8 ld8h(const unsigned short* p) {
    return *reinterpret_cast<const h8*>(p);
}
__device__ __forceinline__ short8 ld8s(const unsigned short* p) {
    return *reinterpret_cast<const short8*>(p);
}
__device__ __forceinline__ f32x4 mf(h8 a, h8 b, f32x4 c) {
    return __builtin_amdgcn_mfma_f32_16x16x32_f16(a, b, c, 0, 0, 0);
}

// ---------------- prep: build f16 weights + leaf lookup tables --------------
__global__ void prep_kernel(const float* __restrict__ emb_pred,
                            const float* __restrict__ emb_var,
                            const float* __restrict__ emb_op,
                            const float* __restrict__ W_pred,
                            const float* __restrict__ W_bin,
                            const float* __restrict__ W_final,
                            unsigned short* __restrict__ ws) {
    for (int i = blockIdx.x * blockDim.x + threadIdx.x; i < WS_USHORTS;
         i += gridDim.x * blockDim.x) {
        float v = 0.f;
        if (i < WFIN_OFF) {                      // W_bin [64][192]
            int n = i / 192, k = i - n * 192, p = k >> 6, j = k & 63;
            if (n < 50 && j < 50) v = W_bin[n * 150 + p * 50 + j];
        } else if (i < EMBO_OFF) {               // W_final [160][64]
            int t = i - WFIN_OFF, o = t >> 6, k = t & 63;
            if (o < 155 && k < 50) v = W_final[o * 50 + k];
        } else if (i < LTAB_OFF) {               // emb_op [100][64]
            int t = i - EMBO_OFF, r = t >> 6, j = t & 63;
            if (j < 50) v = emb_op[r * 50 + j];
        } else {                                 // leaf tables [6][100][64]
            int t = i - LTAB_OFF;
            int p = t / 6400, rest = t - p * 6400, vv = rest >> 6, n = rest & 63;
            if (n < 50) {
                const float* e = (p == 0) ? (emb_pred + vv * 50) : (emb_var + vv * 50);
                const float* wr = W_pred + n * 300 + p * 50;
                float acc = 0.f;
                for (int k = 0; k < 50; ++k) acc += e[k] * wr[k];
                v = acc;
            }
        }
        ws[i] = f2h_bits(v);
    }
}

// one tree node, compile-time N-tile subset [NT0, NT0+NTN)
#define TNODE(NT0, NTN, CL, CR, GN, DST) do {                                   \
    const unsigned short* rl_ = s_x[CL];                                        \
    const unsigned short* rr_ = s_x[CR];                                        \
    int r_ = s_op[(GN) * 16 + l15];                                             \
    h8 aL0 = ld8h(rl_ + l15 * 64 + ((quad ^ (l15 & 7)) << 3));                  \
    h8 aL1 = ld8h(rl_ + l15 * 64 + (((quad + 4) ^ (l15 & 7)) << 3));            \
    h8 aO0 = ld8h(s_embop + r_ * 64 + ((quad ^ (r_ & 7)) << 3));                \
    h8 aO1 = ld8h(s_embop + r_ * 64 + (((quad + 4) ^ (r_ & 7)) << 3));          \
    h8 aR0 = ld8h(rr_ + l15 * 64 + ((quad ^ (l15 & 7)) << 3));                  \
    h8 aR1 = ld8h(rr_ + l15 * 64 + (((quad + 4) ^ (l15 & 7)) << 3));            \
    f32x4 acc_[NTN];                                                            \
    _Pragma("unroll") for (int i_ = 0; i_ < (NTN); ++i_) {                      \
        acc_[i_] = (f32x4){0.f, 0.f, 0.f, 0.f};                                 \
        acc_[i_] = mf(aL0, wb[0][0][(NT0) + i_], acc_[i_]);                     \
        acc_[i_] = mf(aL1, wb[0][1][(NT0) + i_], acc_[i_]);                     \
        acc_[i_] = mf(aO0, wb[1][0][(NT0) + i_], acc_[i_]);                     \
        acc_[i_] = mf(aO1, wb[1][1][(NT0) + i_], acc_[i_]);                     \
        acc_[i_] = mf(aR0, wb[2][0][(NT0) + i_], acc_[i_]);                     \
        acc_[i_] = mf(aR1, wb[2][1][(NT0) + i_], acc_[i_]);                     \
    }                                                                           \
    unsigned short* drow_ = s_x[DST];                                           \
    _Pragma("unroll") for (int i_ = 0; i_ < (NTN); ++i_) {                      \
        int n_ = ((NT0) + i_) * 16 + l15;                                       \
        _Pragma("unroll") for (int q_ = 0; q_ < 4; ++q_) {                      \
            int m_ = quad * 4 + q_;                                             \
            float v_ = fmaxf(acc_[i_][q_] + biasb[(NT0) + i_], 0.f);            \
            drow_[m_ * 64 + (((n_ >> 3) ^ (m_ & 7)) << 3) + (n_ & 7)] = f2h_bits(v_); \
        }                                                                       \
    }                                                                           \
} while (0)

// ---------------- main fused kernel -----------------------------------------
// 1 block = 16 batch, 8 waves (512 thr). 1024-thread blocks hard-cap arch
// VGPRs at 64 (R7/R8/R9: spill, 119 MB scratch) -> back to 512/(,2) = 88 VGPR.
// Whole tree, 7 barriers. s_x row map:
//   leaves 0..63 | lev0 j(32): rd 2j,2j+1 -> wr 2j (in-place, 1 wave/node)
//   lev1 j(16): rd 4j,4j+2 -> 4j (1 wave/node) | lev2 j(8): rd 8j,8j+4 -> 8j
//   lev3 j(4, 2 waves): rd 16j,16j+8 -> 16j+1 (dead) | lev4 j(2, 4 waves):
//   rd 32j+1,32j+17 -> 32j+2 (dead) | root (4 waves): rd 2,34 -> 1 (dead)
__global__ __launch_bounds__(NTH, 2) void formula_kernel(
    const int* __restrict__ pred_ids, const int* __restrict__ arg_ids,
    const int* __restrict__ op_ids,
    const float* __restrict__ b_pred, const float* __restrict__ b_bin,
    const float* __restrict__ b_final,
    const unsigned short* __restrict__ ws,
    float* __restrict__ out)
{
    __shared__ __align__(16) unsigned short s_x[64][1024];         // 131072 B
    __shared__ __align__(16) unsigned short s_embop[100 * 64];     //  12800 B
    __shared__ __align__(8)  unsigned char  s_ids[64][16][8];      //   8192 B
    __shared__ unsigned char s_op[63 * 16 + 16];                   //   1024 B

    const int tid  = threadIdx.x;
    const int b0   = blockIdx.x * NB;
    const int lane = tid & 63;
    const int w    = tid >> 6;       // wave 0..7
    const int l15  = lane & 15;
    const int quad = lane >> 4;
    const int cg   = tid & 7;        // constant col-group (leaf phase)

    // ---- stage op embeddings (swizzled by r&7) ----
    for (int i = tid; i < 800; i += NTH) {
        int r = i >> 3, s = i & 7;
        *reinterpret_cast<short8*>(&s_embop[r * 64 + ((s ^ (r & 7)) << 3)]) =
            ld8s(ws + EMBO_OFF + r * 64 + s * 8);
    }
    // ---- stage ids: s_ids[leaf][m] = {pred, a0..a4, 0, 0} ----
    for (int e = tid; e < 64 * 16; e += NTH) {
        int m = e >> 6, lf = e & 63;
        unsigned char* rec = &s_ids[lf][m][0];
        rec[0] = (unsigned char)pred_ids[(b0 + m) * 64 + lf];
        #pragma unroll
        for (int a = 0; a < 5; ++a)
            rec[1 + a] = (unsigned char)arg_ids[(b0 + m) * 320 + lf * 5 + a];
        rec[6] = 0; rec[7] = 0;
    }
    for (int e = tid; e < 63 * 16; e += NTH) {
        int r = e >> 4, m = e & 15;
        s_op[r * 16 + m] = (unsigned char)op_ids[(b0 + m) * 63 + r];
    }

    // ---- persistent W_bin fragments: all 4 N-tiles in regs (24 VGPR) ----
    short8 wb_raw[3][2][4];
    #pragma unroll
    for (int p = 0; p < 3; ++p)
        #pragma unroll
        for (int h = 0; h < 2; ++h)
            #pragma unroll
            for (int nt = 0; nt < 4; ++nt)
                wb_raw[p][h][nt] = ld8s(ws + WBIN_OFF + (nt * 16 + l15) * 192
                                        + p * 64 + (quad + 4 * h) * 8);
    h8 (&wb)[3][2][4] = reinterpret_cast<h8(&)[3][2][4]>(wb_raw);

    float biasb[4];
    #pragma unroll
    for (int nt = 0; nt < 4; ++nt) {
        int n = nt * 16 + l15;
        biasb[nt] = (n < 50) ? b_bin[n] : 0.f;
    }
    h2 bias2[4];
    #pragma unroll
    for (int k = 0; k < 4; ++k) {
        int n0 = cg * 8 + 2 * k, n1 = n0 + 1;
        bias2[k] = (h2){(_Float16)((n0 < 50) ? b_pred[n0] : 0.f),
                        (_Float16)((n1 < 50) ? b_pred[n1] : 0.f)};
    }
    const h2 z2 = (h2){(_Float16)0.f, (_Float16)0.f};

    __syncthreads();

    // ---- leaf layer: 8192 jobs, 16/thread (unroll 4 to bound VGPR) ----
    #pragma unroll 4
    for (int p4 = 0; p4 < 16; ++p4) {
        int jj  = p4 * NTH + tid;          // 0..8191
        int lf  = jj >> 7;                 // 0..63
        int m   = (jj >> 3) & 15;
        const unsigned int* ivp =
            reinterpret_cast<const unsigned int*>(&s_ids[lf][m][0]);
        unsigned int ix = ivp[0], iy = ivp[1];
        int r0 = ix & 255, r1 = (ix >> 8) & 255, r2 = (ix >> 16) & 255;
        int r3 = ix >> 24, r4 = iy & 255, r5 = (iy >> 8) & 255;
        h2 a0 = bias2[0], a1 = bias2[1], a2 = bias2[2], a3 = bias2[3];
        #define ACCT(ROW, P) {                                                  \
            h8 t_ = ld8h(ws + LTAB_OFF + (P) * 6400 + (ROW) * 64 + cg * 8);     \
            const h2* tp_ = reinterpret_cast<const h2*>(&t_);                   \
            a0 += tp_[0]; a1 += tp_[1]; a2 += tp_[2]; a3 += tp_[3]; }
        ACCT(r0, 0); ACCT(r1, 1); ACCT(r2, 2);
        ACCT(r3, 3); ACCT(r4, 4); ACCT(r5, 5);
        #undef ACCT
        a0 = __builtin_elementwise_max(a0, z2);
        a1 = __builtin_elementwise_max(a1, z2);
        a2 = __builtin_elementwise_max(a2, z2);
        a3 = __builtin_elementwise_max(a3, z2);
        union { h2 h[4]; short8 s; } u;
        u.h[0] = a0; u.h[1] = a1; u.h[2] = a2; u.h[3] = a3;
        *reinterpret_cast<short8*>(
            &s_x[lf][m * 64 + ((cg ^ (m & 7)) << 3)]) = u.s;
    }
    __syncthreads();

    // ---- lev0: 32 nodes, 4 per wave (in-place; 1 wave/node) ----
    #pragma unroll
    for (int i = 0; i < 4; ++i) {
        int j = w + 8 * i;
        TNODE(0, 4, 2 * j, 2 * j + 1, j, 2 * j);
    }
    __syncthreads();
    // ---- lev1: 16 nodes, 2 per wave (in-place) ----
    #pragma unroll
    for (int i = 0; i < 2; ++i) {
        int j = w + 8 * i;
        TNODE(0, 4, 4 * j, 4 * j + 2, 32 + j, 4 * j);
    }
    __syncthreads();
    // ---- lev2: 8 nodes, 1 per wave (in-place) ----
    { int j = w; TNODE(0, 4, 8 * j, 8 * j + 4, 48 + j, 8 * j); }
    __syncthreads();
    // ---- lev3: 4 nodes x 2 waves -> dead row 16j+1 ----
    {
        int j = w >> 1;
        if ((w & 1) == 0) TNODE(0, 2, 16 * j, 16 * j + 8, 56 + j, 16 * j + 1);
        else              TNODE(2, 2, 16 * j, 16 * j + 8, 56 + j, 16 * j + 1);
    }
    __syncthreads();
    // ---- lev4: 2 nodes x 4 waves -> dead row 32j+2 ----
    {
        int j = w >> 2;
        switch (w & 3) {
            case 0: TNODE(0, 1, 32 * j + 1, 32 * j + 17, 60 + j, 32 * j + 2); break;
            case 1: TNODE(1, 1, 32 * j + 1, 32 * j + 17, 60 + j, 32 * j + 2); break;
            case 2: TNODE(2, 1, 32 * j + 1, 32 * j + 17, 60 + j, 32 * j + 2); break;
            default: TNODE(3, 1, 32 * j + 1, 32 * j + 17, 60 + j, 32 * j + 2); break;
        }
    }
    __syncthreads();
    // ---- lev5 (root, waves 0..3): reads rows 2,34 -> dead row 1 ----
    if (w < 4) {
        switch (w) {
            case 0: TNODE(0, 1, 2, 34, 62, 1); break;
            case 1: TNODE(1, 1, 2, 34, 62, 1); break;
            case 2: TNODE(2, 1, 2, 34, 62, 1); break;
            default: TNODE(3, 1, 2, 34, 62, 1); break;
        }
    }
    __syncthreads();

    // ---- final head via MFMA: 10 N-tiles over 8 waves (root = row 1) ----
    auto headtile = [&](int t) {
        f32x4 acc = {0.f, 0.f, 0.f, 0.f};
        int n2 = t * 16 + l15;
        const unsigned short* rroot = s_x[1];
        h8 x0 = ld8h(rroot + l15 * 64 + ((quad ^ (l15 & 7)) << 3));
        h8 x1 = ld8h(rroot + l15 * 64 + (((quad + 4) ^ (l15 & 7)) << 3));
        acc = mf(x0, ld8h(ws + WFIN_OFF + n2 * 64 + quad * 8), acc);
        acc = mf(x1, ld8h(ws + WFIN_OFF + n2 * 64 + (quad + 4) * 8), acc);
        if (n2 < 155) {
            float bias = b_final[n2];
            #pragma unroll
            for (int q = 0; q < 4; ++q) {
                int m = quad * 4 + q;
                out[(b0 + m) * 155 + n2] = acc[q] + bias;
            }
        }
    };
    headtile(w);
    if (w < 2) headtile(8 + w);
}

extern "C" void kernel_launch(void* const* d_in, const int* in_sizes, int n_in,
                              void* d_out, int out_size, void* d_ws, size_t ws_size,
                              hipStream_t stream) {
    const int*   pred_ids = (const int*)  d_in[0];
    const int*   arg_ids  = (const int*)  d_in[1];
    const int*   op_ids   = (const int*)  d_in[2];
    const float* emb_pred = (const float*)d_in[3];
    const float* emb_var  = (const float*)d_in[4];
    const float* emb_op   = (const float*)d_in[5];
    const float* W_pred   = (const float*)d_in[6];
    const float* b_pred   = (const float*)d_in[7];
    const float* W_bin    = (const float*)d_in[8];
    const float* b_bin    = (const float*)d_in[9];
    const float* W_final  = (const float*)d_in[10];
    const float* b_final  = (const float*)d_in[11];
    unsigned short* ws = (unsigned short*)d_ws;
    float* out = (float*)d_out;

    hipLaunchKernelGGL(prep_kernel, dim3(256), dim3(256), 0, stream,
                       emb_pred, emb_var, emb_op, W_pred, W_bin, W_final, ws);
    hipLaunchKernelGGL(formula_kernel, dim3(4096 / NB), dim3(NTH), 0, stream,
                       pred_ids, arg_ids, op_ids, b_pred, b_bin, b_final,
                       (const unsigned short*)ws, out);
}